// Round 1
// baseline (352.717 us; speedup 1.0000x reference)
//
#include <hip/hip_runtime.h>

#define INSZ   2048
#define NH1    256
#define NH2    64
#define NB     8
#define BATCH  16384
#define TM     64
#define BK     32
#define TILES  256   // BATCH / TM

typedef float f4  __attribute__((ext_vector_type(4)));
typedef float f32x4 __attribute__((ext_vector_type(4)));
typedef short bf16x8 __attribute__((ext_vector_type(8)));

__device__ __forceinline__ unsigned short f2bf(float f) {
    unsigned u = __float_as_uint(f);
    u += 0x7fffu + ((u >> 16) & 1u);   // round-to-nearest-even
    return (unsigned short)(u >> 16);
}

__device__ __forceinline__ float clamp01(float v) {
    return fminf(fmaxf(v, 0.0f), 1.0f);
}

__device__ __forceinline__ void store_bf8(short* dst, f4 a, f4 b) {
    bf16x8 r;
    r[0] = (short)f2bf(a[0]); r[1] = (short)f2bf(a[1]);
    r[2] = (short)f2bf(a[2]); r[3] = (short)f2bf(a[3]);
    r[4] = (short)f2bf(b[0]); r[5] = (short)f2bf(b[1]);
    r[6] = (short)f2bf(b[2]); r[7] = (short)f2bf(b[3]);
    *(bf16x8*)dst = r;
}

__device__ __forceinline__ bf16x8 pack_bf8(f4 a, f4 b) {
    bf16x8 r;
    r[0] = (short)f2bf(a[0]); r[1] = (short)f2bf(a[1]);
    r[2] = (short)f2bf(a[2]); r[3] = (short)f2bf(a[3]);
    r[4] = (short)f2bf(b[0]); r[5] = (short)f2bf(b[1]);
    r[6] = (short)f2bf(b[2]); r[7] = (short)f2bf(b[3]);
    return r;
}

// ---------------- K1: histogram + exclusive scan (single block) ----------------
__global__ void bucket_count(const int* __restrict__ idx, int* __restrict__ meta) {
    __shared__ int scnt[NB];
    int t = threadIdx.x;
    if (t < NB) scnt[t] = 0;
    __syncthreads();
    int local[NB];
#pragma unroll
    for (int bb = 0; bb < NB; bb++) local[bb] = 0;
    for (int i = t; i < BATCH; i += 1024) {
        int b = idx[i];
#pragma unroll
        for (int bb = 0; bb < NB; bb++) local[bb] += (b == bb) ? 1 : 0;
    }
#pragma unroll
    for (int bb = 0; bb < NB; bb++) {
        int v = local[bb];
        v += __shfl_xor(v, 1);  v += __shfl_xor(v, 2);  v += __shfl_xor(v, 4);
        v += __shfl_xor(v, 8);  v += __shfl_xor(v, 16); v += __shfl_xor(v, 32);
        if ((t & 63) == 0) atomicAdd(&scnt[bb], v);
    }
    __syncthreads();
    if (t == 0) {
        int running = 0;
        for (int bb = 0; bb < NB; bb++) {
            int c = scnt[bb];
            meta[bb]      = c;        // count
            meta[8 + bb]  = running;  // offset
            meta[16 + bb] = running;  // cursor for scatter
            running += c;
        }
    }
}

// ---------------- K2: scatter sample ids into bucket-sorted order ----------------
__global__ void bucket_scatter(const int* __restrict__ idx, int* __restrict__ meta,
                               int* __restrict__ order) {
    __shared__ int wcnt[16][NB];
    __shared__ int sbase[NB];
    int t = threadIdx.x;
    int i = blockIdx.x * 1024 + t;
    int b = idx[i];
    int wv = t >> 6, lane = t & 63;
    unsigned long long mymask = 0;
#pragma unroll
    for (int bb = 0; bb < NB; bb++) {
        unsigned long long m = __ballot(b == bb);
        if (b == bb) mymask = m;
        if (lane == bb) wcnt[wv][bb] = (int)__popcll(m);
    }
    int myrank = (int)__popcll(mymask & ((1ull << lane) - 1ull));
    __syncthreads();
    if (t < NB) {
        int sum = 0;
        for (int w2 = 0; w2 < 16; w2++) {
            int c = wcnt[w2][t];
            wcnt[w2][t] = sum;   // exclusive prefix per wave
            sum += c;
        }
        sbase[t] = atomicAdd(&meta[16 + t], sum);
    }
    __syncthreads();
    int pos = sbase[b] + wcnt[wv][b] + myrank;
    order[pos] = i;
}

// ---------------- main: fused 3-layer bucketed MLP ----------------
__global__ __launch_bounds__(256, 2) void fused_mlp(
    const float* __restrict__ x, const int* __restrict__ meta,
    const int* __restrict__ order,
    const float* __restrict__ W1, const float* __restrict__ b1,
    const float* __restrict__ W2, const float* __restrict__ b2,
    const float* __restrict__ W3, const float* __restrict__ b3,
    float* __restrict__ out)
{
    int bkt  = blockIdx.x >> 8;     // bucket-major: L2-friendly per-XCD weight reuse
    int tile = blockIdx.x & 255;
    int cnt  = meta[bkt];
    int base = tile * TM;
    if (base >= cnt) return;
    int off = meta[8 + bkt];

    __shared__ short sX[TM][BK];            // 4 KB   x tile (bf16)
    __shared__ short sB[NH1][BK];           // 16 KB  W1 tile (bf16)
    __shared__ short sH1[TM][NH1 + 8];      // 33 KB  h1 (padded stride 264: no bank conflict)
    __shared__ int   sRow[TM];
    __shared__ float sPart[4][TM];

    int t = threadIdx.x;
    int lane = t & 63, w = t >> 6;
    int l15 = lane & 15, quad = lane >> 4;

    if (t < TM) {
        int ii = base + t;
        if (ii >= cnt) ii = cnt - 1;        // duplicate last valid row for tail
        sRow[t] = order[off + ii];
    }
    __syncthreads();

    // staging assignment: X: thread t -> row t>>2, 8 floats at (t&3)*8
    //                     W: thread t -> row t, 32 floats
    int xrow = t >> 2, xkc = t & 3;
    const float* xrp = x + (size_t)sRow[xrow] * INSZ + xkc * 8;
    const float* wrp = W1 + (size_t)(bkt * NH1 + t) * INSZ;

    f32x4 acc[4][4];
#pragma unroll
    for (int mi = 0; mi < 4; mi++)
#pragma unroll
        for (int ni = 0; ni < 4; ni++) acc[mi][ni] = (f32x4)0.0f;

    // preload first x chunk
    f4 xa = *(const f4*)(xrp);
    f4 xb = *(const f4*)(xrp + 4);

#pragma unroll 1
    for (int k0 = 0; k0 < INSZ; k0 += BK) {
        // issue W loads for this step (L2-resident after first use)
        f4 wv0[8];
#pragma unroll
        for (int c = 0; c < 8; c++) wv0[c] = *(const f4*)(wrp + k0 + c * 4);
        // store current x chunk (already in regs)
        store_bf8(&sX[xrow][xkc * 8], xa, xb);
        // prefetch next x chunk (keeps HBM pipe full across the barrier)
        int kn = k0 + BK;
        f4 xna = xa, xnb = xb;
        if (kn < INSZ) { xna = *(const f4*)(xrp + kn); xnb = *(const f4*)(xrp + kn + 4); }
        // convert + store W tile
#pragma unroll
        for (int c = 0; c < 4; c++) store_bf8(&sB[t][c * 8], wv0[2 * c], wv0[2 * c + 1]);
        __syncthreads();

        bf16x8 a[4], bf[4];
#pragma unroll
        for (int mi = 0; mi < 4; mi++)
            a[mi] = *(const bf16x8*)&sX[mi * 16 + l15][quad * 8];
#pragma unroll
        for (int ni = 0; ni < 4; ni++)
            bf[ni] = *(const bf16x8*)&sB[w * 64 + ni * 16 + l15][quad * 8];
#pragma unroll
        for (int mi = 0; mi < 4; mi++)
#pragma unroll
            for (int ni = 0; ni < 4; ni++)
                acc[mi][ni] = __builtin_amdgcn_mfma_f32_16x16x32_bf16(
                    a[mi], bf[ni], acc[mi][ni], 0, 0, 0);
        __syncthreads();
        xa = xna; xb = xnb;
    }

    // epilogue layer 1: bias + clip01 -> sH1 (bf16)
#pragma unroll
    for (int ni = 0; ni < 4; ni++) {
        int col = w * 64 + ni * 16 + l15;
        float bias = b1[bkt * NH1 + col];
#pragma unroll
        for (int mi = 0; mi < 4; mi++) {
#pragma unroll
            for (int r = 0; r < 4; r++) {
                int row = mi * 16 + quad * 4 + r;
                float v = clamp01(acc[mi][ni][r] + bias);
                sH1[row][col] = (short)f2bf(v);
            }
        }
    }
    __syncthreads();

    // layer 2: h2(64x64) = h1 @ W2_b^T, wave w owns output cols w*16..w*16+15
    f32x4 acc2[4];
#pragma unroll
    for (int mi = 0; mi < 4; mi++) acc2[mi] = (f32x4)0.0f;
    int n2 = w * 16 + l15;                       // output feature 0..63
    const float* w2rp = W2 + (size_t)(bkt * NH2 + n2) * NH1;
#pragma unroll
    for (int k0 = 0; k0 < NH1; k0 += 32) {
        const float* p = w2rp + k0 + quad * 8;
        f4 v0 = *(const f4*)p;
        f4 v1 = *(const f4*)(p + 4);
        bf16x8 bfr = pack_bf8(v0, v1);
#pragma unroll
        for (int mi = 0; mi < 4; mi++) {
            bf16x8 af = *(const bf16x8*)&sH1[mi * 16 + l15][k0 + quad * 8];
            acc2[mi] = __builtin_amdgcn_mfma_f32_16x16x32_bf16(af, bfr, acc2[mi], 0, 0, 0);
        }
    }

    // epilogue layer 2 + layer 3 partial dot
    float bias2 = b2[bkt * NH2 + n2];
    float w3v   = W3[bkt * NH2 + n2];
#pragma unroll
    for (int mi = 0; mi < 4; mi++) {
#pragma unroll
        for (int r = 0; r < 4; r++) {
            float h2 = clamp01(acc2[mi][r] + bias2);
            float p = h2 * w3v;
            p += __shfl_xor(p, 1); p += __shfl_xor(p, 2);
            p += __shfl_xor(p, 4); p += __shfl_xor(p, 8);
            if (l15 == 0) sPart[w][mi * 16 + quad * 4 + r] = p;
        }
    }
    __syncthreads();
    if (t < TM) {
        int ii = base + t;
        if (ii < cnt) {
            float o = sPart[0][t] + sPart[1][t] + sPart[2][t] + sPart[3][t] + b3[bkt];
            out[sRow[t]] = o;
        }
    }
}

// ---------------- fallback (tiny workspace): naive fp32, correct but slow ----------------
__global__ void naive_mlp(const float* __restrict__ x, const int* __restrict__ idx,
                          const float* __restrict__ W1, const float* __restrict__ b1,
                          const float* __restrict__ W2, const float* __restrict__ b2,
                          const float* __restrict__ W3, const float* __restrict__ b3,
                          float* __restrict__ out)
{
    int i = blockIdx.x;
    int b = idx[i];
    __shared__ float sx[INSZ];
    __shared__ float sh1[NH1];
    __shared__ float sh2[NH2];
    for (int t = threadIdx.x; t < INSZ; t += 256) sx[t] = x[(size_t)i * INSZ + t];
    __syncthreads();
    int j = threadIdx.x;
    {
        const float* wr = W1 + (size_t)(b * NH1 + j) * INSZ;
        float acc = b1[b * NH1 + j];
        for (int k = 0; k < INSZ; k++) acc += sx[k] * wr[k];
        sh1[j] = fminf(fmaxf(acc, 0.f), 1.f);
    }
    __syncthreads();
    if (j < NH2) {
        const float* wr = W2 + (size_t)(b * NH2 + j) * NH1;
        float acc = b2[b * NH2 + j];
        for (int k = 0; k < NH1; k++) acc += sh1[k] * wr[k];
        sh2[j] = fminf(fmaxf(acc, 0.f), 1.f);
    }
    __syncthreads();
    if (j == 0) {
        float acc = b3[b];
        for (int k = 0; k < NH2; k++) acc += sh2[k] * W3[b * NH2 + k];
        out[i] = acc;
    }
}

extern "C" void kernel_launch(void* const* d_in, const int* in_sizes, int n_in,
                              void* d_out, int out_size, void* d_ws, size_t ws_size,
                              hipStream_t stream) {
    const float* x  = (const float*)d_in[0];
    const int* bidx = (const int*)d_in[1];
    const float* W1 = (const float*)d_in[2];
    const float* b1 = (const float*)d_in[3];
    const float* W2 = (const float*)d_in[4];
    const float* b2 = (const float*)d_in[5];
    const float* W3 = (const float*)d_in[6];
    const float* b3 = (const float*)d_in[7];
    float* out = (float*)d_out;

    const size_t need = 128 + (size_t)BATCH * sizeof(int);
    if (ws_size >= need) {
        int* meta  = (int*)d_ws;                      // cnt[8], offs[8], cursors[8]
        int* order = (int*)((char*)d_ws + 128);       // bucket-sorted sample ids
        bucket_count<<<1, 1024, 0, stream>>>(bidx, meta);
        bucket_scatter<<<BATCH / 1024, 1024, 0, stream>>>(bidx, meta, order);
        fused_mlp<<<NB * TILES, 256, 0, stream>>>(x, meta, order, W1, b1, W2, b2, W3, b3, out);
    } else {
        naive_mlp<<<BATCH, 256, 0, stream>>>(x, bidx, W1, b1, W2, b2, W3, b3, out);
    }
}

// Round 2
// 308.849 us; speedup vs baseline: 1.1420x; 1.1420x over previous
//
#include <hip/hip_runtime.h>

#define INSZ   2048
#define NH1    256
#define NH2    64
#define NB     8
#define BATCH  16384

// ---- new fast path geometry ----
#define TS     32          // rows per tile
#define WSTRIDE 40         // shorts per W1/X row in LDS (32 data + 8 pad; 80 B: 16B-aligned, 2-way banks)
#define SBT    (256 * WSTRIDE)   // 10240 shorts per staged W1 k-tile
#define SXT    (TS * WSTRIDE)    // 1280 shorts per staged x k-tile
#define NWORK  520         // max tiles: 16384/32 + 8
#define W1P_SHORTS (NB * 64 * SBT)      // 5,242,880 shorts = 10.49 MB
#define W2P_SHORTS (NB * 8 * 4 * 64 * 8) // 131072 shorts = 256 KB

// ws layout (bytes)
#define META_OFF  0            // 32 ints: cnt[8], off[8], cursor[8], spare
#define WORK_OFF  1024         // 520 int2
#define ORDER_OFF 8192         // 16384 ints
#define W1P_OFF   73728
#define W2P_OFF   (W1P_OFF + W1P_SHORTS * 2)         // 10,559,488
#define WS_NEED   (W2P_OFF + W2P_SHORTS * 2)         // ~10.82 MB
#define WS_NEED_SMALL (128 + BATCH * 4)              // round-1 fallback layout

typedef float f4  __attribute__((ext_vector_type(4)));
typedef float f32x4 __attribute__((ext_vector_type(4)));
typedef short bf16x8 __attribute__((ext_vector_type(8)));

__device__ __forceinline__ unsigned short f2bf(float f) {
    unsigned u = __float_as_uint(f);
    u += 0x7fffu + ((u >> 16) & 1u);   // RNE
    return (unsigned short)(u >> 16);
}
__device__ __forceinline__ float clamp01(float v) { return fminf(fmaxf(v, 0.0f), 1.0f); }
__device__ __forceinline__ unsigned pack2(float a, float b) {
    return (unsigned)f2bf(a) | ((unsigned)f2bf(b) << 16);
}

// async global -> LDS, 16 B per lane; ldst must be wave-uniform
__device__ __forceinline__ void glds16(const short* gsrc, short* ldst) {
    __builtin_amdgcn_global_load_lds(
        (const __attribute__((address_space(1))) unsigned int*)gsrc,
        (__attribute__((address_space(3))) unsigned int*)ldst, 16, 0, 0);
}

// stage one 20480-B W1 k-tile (1280 16-B chunks) with 512 threads
__device__ __forceinline__ void stage_w(const short* g, short* l, int w64, int lane, int t) {
    glds16(g + (size_t)(w64 + lane) * 8,        l + (size_t)w64 * 8);
    glds16(g + (size_t)(512 + w64 + lane) * 8,  l + (size_t)(512 + w64) * 8);
    if (t < 256)
        glds16(g + (size_t)(1024 + w64 + lane) * 8, l + (size_t)(1024 + w64) * 8);
}

// ============================ pre-pass kernels ============================

__global__ void k_zero(int* meta) {
    if (threadIdx.x < 32) meta[threadIdx.x] = 0;
}

__global__ void k_count(const int* __restrict__ idx, int* __restrict__ meta) {
    int t = blockIdx.x * 1024 + threadIdx.x;   // 4096 threads
    int local[NB];
#pragma unroll
    for (int b = 0; b < NB; b++) local[b] = 0;
    for (int i = t; i < BATCH; i += 4096) {
        int b = idx[i];
#pragma unroll
        for (int bb = 0; bb < NB; bb++) local[bb] += (b == bb) ? 1 : 0;
    }
#pragma unroll
    for (int bb = 0; bb < NB; bb++) {
        int v = local[bb];
        v += __shfl_xor(v, 1);  v += __shfl_xor(v, 2);  v += __shfl_xor(v, 4);
        v += __shfl_xor(v, 8);  v += __shfl_xor(v, 16); v += __shfl_xor(v, 32);
        if ((threadIdx.x & 63) == 0) atomicAdd(&meta[bb], v);
    }
}

__global__ void k_scan(int* __restrict__ meta, int2* __restrict__ work) {
    __shared__ int ts[NB + 1];
    int t = threadIdx.x;
    if (t == 0) {
        int run = 0, trun = 0;
        for (int b = 0; b < NB; b++) {
            int c = meta[b];
            meta[8 + b]  = run;
            meta[16 + b] = run;   // scatter cursor
            run += c;
            ts[b] = trun;
            trun += (c + TS - 1) / TS;
        }
        ts[NB] = trun;
    }
    __syncthreads();
    for (int i = t; i < NWORK; i += blockDim.x) {
        int b = -1;
#pragma unroll
        for (int bb = 0; bb < NB; bb++)
            if (i >= ts[bb] && i < ts[bb + 1]) b = bb;
        int2 v;
        if (b >= 0) { v.x = b; v.y = (i - ts[b]) * TS; }
        else        { v.x = -1; v.y = 0; }
        work[i] = v;
    }
}

__global__ void k_scatter(const int* __restrict__ idx, int* __restrict__ meta,
                          int* __restrict__ order) {
    __shared__ int wcnt[16][NB];
    __shared__ int sbase[NB];
    int t = threadIdx.x;
    int i = blockIdx.x * 1024 + t;
    int b = idx[i];
    int wv = t >> 6, lane = t & 63;
    unsigned long long mymask = 0;
#pragma unroll
    for (int bb = 0; bb < NB; bb++) {
        unsigned long long m = __ballot(b == bb);
        if (b == bb) mymask = m;
        if (lane == bb) wcnt[wv][bb] = (int)__popcll(m);
    }
    int myrank = (int)__popcll(mymask & ((1ull << lane) - 1ull));
    __syncthreads();
    if (t < NB) {
        int sum = 0;
        for (int w2 = 0; w2 < 16; w2++) { int c = wcnt[w2][t]; wcnt[w2][t] = sum; sum += c; }
        sbase[t] = atomicAdd(&meta[16 + t], sum);
    }
    __syncthreads();
    order[sbase[b] + wcnt[wv][b] + myrank] = i;
}

// pack W1 -> bf16 LDS-image layout [bkt][kb][col(256)][WSTRIDE], pad k2>=32 zero
// pack W2 -> bf16 fragment layout [bkt][kb2(8)][wc(4)][lane(64)][8]
__global__ void k_pack(const float* __restrict__ W1, const float* __restrict__ W2,
                       unsigned* __restrict__ W1p, unsigned* __restrict__ W2p) {
    if (blockIdx.x < (W1P_SHORTS / 2) / 256) {
        int o2 = blockIdx.x * 256 + threadIdx.x;
        int o  = o2 * 2;
        int k2  = o % WSTRIDE;
        int col = (o / WSTRIDE) % 256;
        int kb  = (o / SBT) % 64;
        int bkt = o / (SBT * 64);
        const float* wr = W1 + (size_t)(bkt * 256 + col) * INSZ + kb * 32;
        unsigned lo = (k2 < 32)     ? f2bf(wr[k2])     : 0u;
        unsigned hi = (k2 + 1 < 32) ? f2bf(wr[k2 + 1]) : 0u;
        W1p[o2] = lo | (hi << 16);
    } else {
        int o2 = (blockIdx.x - (W1P_SHORTS / 2) / 256) * 256 + threadIdx.x;
        if (o2 >= W2P_SHORTS / 2) return;
        int o = o2 * 2;
        int j    = o % 8;
        int lane = (o / 8) % 64;
        int wc   = (o / 512) % 4;
        int kb   = (o / 2048) % 8;
        int bkt  = o / 16384;
        int l15 = lane & 15, quad = lane >> 4;
        const float* wr = W2 + (size_t)(bkt * 64 + wc * 16 + l15) * NH1 + kb * 32 + quad * 8 + j;
        W2p[o2] = pack2(wr[0], wr[1]);
    }
}

// ============================ main fused kernel ============================

__global__ __launch_bounds__(512, 4) void fused_main(
    const float* __restrict__ x, const int* __restrict__ meta,
    const int2* __restrict__ work, const int* __restrict__ order,
    const short* __restrict__ W1p, const short* __restrict__ W2p,
    const float* __restrict__ b1, const float* __restrict__ b2,
    const float* __restrict__ W3, const float* __restrict__ b3,
    float* __restrict__ out)
{
    int2 wk = work[blockIdx.x];
    if (wk.x < 0) return;
    const int bkt = wk.x, base = wk.y;
    const int cnt = meta[bkt], off = meta[8 + bkt];

    __shared__ short sB[2 * SBT];        // 40 KB  W1 k-tiles (dbuf)
    __shared__ short sX[2 * SXT];        // 5 KB   x k-tiles (dbuf)
    __shared__ short sH1[TS * 264];      // 16.5 KB h1
    __shared__ int   sRowA[TS];
    __shared__ float sPart[4][TS];

    const int t = threadIdx.x;
    const int lane = t & 63, w = t >> 6;
    const int l15 = lane & 15, quad = lane >> 4;
    const int wr = w >> 2, wc = w & 3;
    const int w64 = w << 6;

    if (t < TS) {
        int ii = base + t; if (ii >= cnt) ii = cnt - 1;
        sRowA[t] = order[off + ii];
    }
    __syncthreads();

    const float* xrp = x + (size_t)sRowA[t >> 4] * INSZ + (t & 15) * 2;
    const short* wtile = W1p + (size_t)bkt * 64 * SBT;
    const int sxoff = (t >> 4) * WSTRIDE + (t & 15) * 2;

    // prologue: tile 0 into buffers, x tile 1 into regs
    stage_w(wtile, sB, w64, lane, t);
    float2 xv = *(const float2*)xrp;
    __syncthreads();                               // drain glds tile0 + xv
    *(unsigned*)&sX[sxoff] = pack2(xv.x, xv.y);
    xv = *(const float2*)(xrp + 32);
    __syncthreads();                               // sX[0] visible

    f32x4 acc[4];
#pragma unroll
    for (int ni = 0; ni < 4; ni++) acc[ni] = (f32x4)0.0f;

#pragma unroll 1
    for (int kb = 0; kb < 64; kb++) {
        const int p = kb & 1;
        const short* sBp = sB + p * SBT;
        const short* sXp = sX + p * SXT;
        if (kb < 63) {
            stage_w(wtile + (size_t)(kb + 1) * SBT, sB + (p ^ 1) * SBT, w64, lane, t);
            *(unsigned*)&sX[(p ^ 1) * SXT + sxoff] = pack2(xv.x, xv.y);
        }
        if (kb < 62) xv = *(const float2*)(xrp + (kb + 2) * 32);

        bf16x8 a = *(const bf16x8*)&sXp[(wr * 16 + l15) * WSTRIDE + quad * 8];
#pragma unroll
        for (int ni = 0; ni < 4; ni++) {
            bf16x8 bfr = *(const bf16x8*)&sBp[(wc * 64 + ni * 16 + l15) * WSTRIDE + quad * 8];
            acc[ni] = __builtin_amdgcn_mfma_f32_16x16x32_bf16(a, bfr, acc[ni], 0, 0, 0);
        }
        __syncthreads();                           // drains glds(kb+1) + sX writes
    }

    // epilogue layer 1: bias + clip -> sH1 (bf16, stride 264)
#pragma unroll
    for (int ni = 0; ni < 4; ni++) {
        int col = wc * 64 + ni * 16 + l15;
        float bias = b1[bkt * NH1 + col];
#pragma unroll
        for (int r = 0; r < 4; r++) {
            int row = wr * 16 + quad * 4 + r;
            sH1[row * 264 + col] = (short)f2bf(clamp01(acc[ni][r] + bias));
        }
    }
    __syncthreads();

    // layer 2: wave (wr,wc) -> rows wr*16..+16, cols wc*16..+16; K=256
    f32x4 acc2 = (f32x4)0.0f;
    const short* w2t = W2p + (size_t)bkt * (8 * 4 * 64 * 8);
#pragma unroll
    for (int kb2 = 0; kb2 < 8; kb2++) {
        bf16x8 a2  = *(const bf16x8*)&sH1[(wr * 16 + l15) * 264 + kb2 * 32 + quad * 8];
        bf16x8 b2f = *(const bf16x8*)&w2t[((kb2 * 4 + wc) * 64 + lane) * 8];
        acc2 = __builtin_amdgcn_mfma_f32_16x16x32_bf16(a2, b2f, acc2, 0, 0, 0);
    }

    // epilogue layer 2 + layer 3 partial dot (reduce over 16 cols per wc-group)
    int n2 = wc * 16 + l15;
    float bias2 = b2[bkt * NH2 + n2];
    float w3v   = W3[bkt * NH2 + n2];
#pragma unroll
    for (int r = 0; r < 4; r++) {
        float h2 = clamp01(acc2[r] + bias2);
        float pp = h2 * w3v;
        pp += __shfl_xor(pp, 1); pp += __shfl_xor(pp, 2);
        pp += __shfl_xor(pp, 4); pp += __shfl_xor(pp, 8);
        if (l15 == 0) sPart[wc][wr * 16 + quad * 4 + r] = pp;
    }
    __syncthreads();
    if (t < TS && base + t < cnt) {
        out[sRowA[t]] = sPart[0][t] + sPart[1][t] + sPart[2][t] + sPart[3][t] + b3[bkt];
    }
}

// ============================ round-1 fallback path ============================

__global__ void bucket_count1(const int* __restrict__ idx, int* __restrict__ meta) {
    __shared__ int scnt[NB];
    int t = threadIdx.x;
    if (t < NB) scnt[t] = 0;
    __syncthreads();
    int local[NB];
#pragma unroll
    for (int bb = 0; bb < NB; bb++) local[bb] = 0;
    for (int i = t; i < BATCH; i += 1024) {
        int b = idx[i];
#pragma unroll
        for (int bb = 0; bb < NB; bb++) local[bb] += (b == bb) ? 1 : 0;
    }
#pragma unroll
    for (int bb = 0; bb < NB; bb++) {
        int v = local[bb];
        v += __shfl_xor(v, 1);  v += __shfl_xor(v, 2);  v += __shfl_xor(v, 4);
        v += __shfl_xor(v, 8);  v += __shfl_xor(v, 16); v += __shfl_xor(v, 32);
        if ((t & 63) == 0) atomicAdd(&scnt[bb], v);
    }
    __syncthreads();
    if (t == 0) {
        int running = 0;
        for (int bb = 0; bb < NB; bb++) {
            int c = scnt[bb];
            meta[bb] = c; meta[8 + bb] = running; meta[16 + bb] = running;
            running += c;
        }
    }
}

__device__ __forceinline__ void store_bf8(short* dst, f4 a, f4 b) {
    bf16x8 r;
    r[0] = (short)f2bf(a[0]); r[1] = (short)f2bf(a[1]);
    r[2] = (short)f2bf(a[2]); r[3] = (short)f2bf(a[3]);
    r[4] = (short)f2bf(b[0]); r[5] = (short)f2bf(b[1]);
    r[6] = (short)f2bf(b[2]); r[7] = (short)f2bf(b[3]);
    *(bf16x8*)dst = r;
}
__device__ __forceinline__ bf16x8 pack_bf8(f4 a, f4 b) {
    bf16x8 r;
    r[0] = (short)f2bf(a[0]); r[1] = (short)f2bf(a[1]);
    r[2] = (short)f2bf(a[2]); r[3] = (short)f2bf(a[3]);
    r[4] = (short)f2bf(b[0]); r[5] = (short)f2bf(b[1]);
    r[6] = (short)f2bf(b[2]); r[7] = (short)f2bf(b[3]);
    return r;
}

__global__ __launch_bounds__(256, 2) void fused_mlp_small(
    const float* __restrict__ x, const int* __restrict__ meta,
    const int* __restrict__ order,
    const float* __restrict__ W1, const float* __restrict__ b1,
    const float* __restrict__ W2, const float* __restrict__ b2,
    const float* __restrict__ W3, const float* __restrict__ b3,
    float* __restrict__ out)
{
    int bkt  = blockIdx.x >> 8;
    int tile = blockIdx.x & 255;
    int cnt  = meta[bkt];
    int base = tile * 64;
    if (base >= cnt) return;
    int off = meta[8 + bkt];

    __shared__ short sXs[64][32];
    __shared__ short sBs[NH1][32];
    __shared__ short sH1s[64][NH1 + 8];
    __shared__ int   sRow[64];
    __shared__ float sPart[4][64];

    int t = threadIdx.x;
    int lane = t & 63, w = t >> 6;
    int l15 = lane & 15, quad = lane >> 4;

    if (t < 64) {
        int ii = base + t; if (ii >= cnt) ii = cnt - 1;
        sRow[t] = order[off + ii];
    }
    __syncthreads();

    int xrow = t >> 2, xkc = t & 3;
    const float* xrp = x + (size_t)sRow[xrow] * INSZ + xkc * 8;
    const float* wrp = W1 + (size_t)(bkt * NH1 + t) * INSZ;

    f32x4 acc[4][4];
#pragma unroll
    for (int mi = 0; mi < 4; mi++)
#pragma unroll
        for (int ni = 0; ni < 4; ni++) acc[mi][ni] = (f32x4)0.0f;

    f4 xa = *(const f4*)(xrp);
    f4 xb = *(const f4*)(xrp + 4);

#pragma unroll 1
    for (int k0 = 0; k0 < INSZ; k0 += 32) {
        f4 wv0[8];
#pragma unroll
        for (int c = 0; c < 8; c++) wv0[c] = *(const f4*)(wrp + k0 + c * 4);
        store_bf8(&sXs[xrow][xkc * 8], xa, xb);
        int kn = k0 + 32;
        f4 xna = xa, xnb = xb;
        if (kn < INSZ) { xna = *(const f4*)(xrp + kn); xnb = *(const f4*)(xrp + kn + 4); }
#pragma unroll
        for (int c = 0; c < 4; c++) store_bf8(&sBs[t][c * 8], wv0[2 * c], wv0[2 * c + 1]);
        __syncthreads();
        bf16x8 a[4], bf[4];
#pragma unroll
        for (int mi = 0; mi < 4; mi++) a[mi] = *(const bf16x8*)&sXs[mi * 16 + l15][quad * 8];
#pragma unroll
        for (int ni = 0; ni < 4; ni++) bf[ni] = *(const bf16x8*)&sBs[w * 64 + ni * 16 + l15][quad * 8];
#pragma unroll
        for (int mi = 0; mi < 4; mi++)
#pragma unroll
            for (int ni = 0; ni < 4; ni++)
                acc[mi][ni] = __builtin_amdgcn_mfma_f32_16x16x32_bf16(a[mi], bf[ni], acc[mi][ni], 0, 0, 0);
        __syncthreads();
        xa = xna; xb = xnb;
    }
#pragma unroll
    for (int ni = 0; ni < 4; ni++) {
        int col = w * 64 + ni * 16 + l15;
        float bias = b1[bkt * NH1 + col];
#pragma unroll
        for (int mi = 0; mi < 4; mi++)
#pragma unroll
            for (int r = 0; r < 4; r++)
                sH1s[mi * 16 + quad * 4 + r][col] = (short)f2bf(clamp01(acc[mi][ni][r] + bias));
    }
    __syncthreads();
    f32x4 acc2[4];
#pragma unroll
    for (int mi = 0; mi < 4; mi++) acc2[mi] = (f32x4)0.0f;
    int n2 = w * 16 + l15;
    const float* w2rp = W2 + (size_t)(bkt * NH2 + n2) * NH1;
#pragma unroll
    for (int k0 = 0; k0 < NH1; k0 += 32) {
        const float* p = w2rp + k0 + quad * 8;
        bf16x8 bfr = pack_bf8(*(const f4*)p, *(const f4*)(p + 4));
#pragma unroll
        for (int mi = 0; mi < 4; mi++) {
            bf16x8 af = *(const bf16x8*)&sH1s[mi * 16 + l15][k0 + quad * 8];
            acc2[mi] = __builtin_amdgcn_mfma_f32_16x16x32_bf16(af, bfr, acc2[mi], 0, 0, 0);
        }
    }
    float bias2 = b2[bkt * NH2 + n2];
    float w3v   = W3[bkt * NH2 + n2];
#pragma unroll
    for (int mi = 0; mi < 4; mi++)
#pragma unroll
        for (int r = 0; r < 4; r++) {
            float h2 = clamp01(acc2[mi][r] + bias2);
            float pp = h2 * w3v;
            pp += __shfl_xor(pp, 1); pp += __shfl_xor(pp, 2);
            pp += __shfl_xor(pp, 4); pp += __shfl_xor(pp, 8);
            if (l15 == 0) sPart[w][mi * 16 + quad * 4 + r] = pp;
        }
    __syncthreads();
    if (t < 64 && base + t < cnt)
        out[sRow[t]] = sPart[0][t] + sPart[1][t] + sPart[2][t] + sPart[3][t] + b3[bkt];
}

// ============================ naive fallback ============================

__global__ void naive_mlp(const float* __restrict__ x, const int* __restrict__ idx,
                          const float* __restrict__ W1, const float* __restrict__ b1,
                          const float* __restrict__ W2, const float* __restrict__ b2,
                          const float* __restrict__ W3, const float* __restrict__ b3,
                          float* __restrict__ out)
{
    int i = blockIdx.x;
    int b = idx[i];
    __shared__ float sx[INSZ];
    __shared__ float sh1[NH1];
    __shared__ float sh2[NH2];
    for (int t = threadIdx.x; t < INSZ; t += 256) sx[t] = x[(size_t)i * INSZ + t];
    __syncthreads();
    int j = threadIdx.x;
    {
        const float* wr = W1 + (size_t)(b * NH1 + j) * INSZ;
        float acc = b1[b * NH1 + j];
        for (int k = 0; k < INSZ; k++) acc += sx[k] * wr[k];
        sh1[j] = fminf(fmaxf(acc, 0.f), 1.f);
    }
    __syncthreads();
    if (j < NH2) {
        const float* wr = W2 + (size_t)(b * NH2 + j) * NH1;
        float acc = b2[b * NH2 + j];
        for (int k = 0; k < NH1; k++) acc += sh1[k] * wr[k];
        sh2[j] = fminf(fmaxf(acc, 0.f), 1.f);
    }
    __syncthreads();
    if (j == 0) {
        float acc = b3[b];
        for (int k = 0; k < NH2; k++) acc += sh2[k] * W3[b * NH2 + k];
        out[i] = acc;
    }
}

extern "C" void kernel_launch(void* const* d_in, const int* in_sizes, int n_in,
                              void* d_out, int out_size, void* d_ws, size_t ws_size,
                              hipStream_t stream) {
    const float* x  = (const float*)d_in[0];
    const int* bidx = (const int*)d_in[1];
    const float* W1 = (const float*)d_in[2];
    const float* b1 = (const float*)d_in[3];
    const float* W2 = (const float*)d_in[4];
    const float* b2 = (const float*)d_in[5];
    const float* W3 = (const float*)d_in[6];
    const float* b3 = (const float*)d_in[7];
    float* out = (float*)d_out;

    if (ws_size >= (size_t)WS_NEED) {
        char* ws = (char*)d_ws;
        int*      meta  = (int*)(ws + META_OFF);
        int2*     work  = (int2*)(ws + WORK_OFF);
        int*      order = (int*)(ws + ORDER_OFF);
        unsigned* W1p   = (unsigned*)(ws + W1P_OFF);
        unsigned* W2p   = (unsigned*)(ws + W2P_OFF);

        k_zero<<<1, 64, 0, stream>>>(meta);
        k_count<<<4, 1024, 0, stream>>>(bidx, meta);
        k_scan<<<1, 512, 0, stream>>>(meta, work);
        k_scatter<<<BATCH / 1024, 1024, 0, stream>>>(bidx, meta, order);
        int packGrid = (W1P_SHORTS / 2) / 256 + (W2P_SHORTS / 2 + 255) / 256;
        k_pack<<<packGrid, 256, 0, stream>>>(W1, W2, W1p, W2p);
        fused_main<<<NWORK, 512, 0, stream>>>(x, meta, work, order,
                                              (const short*)W1p, (const short*)W2p,
                                              b1, b2, W3, b3, out);
    } else if (ws_size >= (size_t)WS_NEED_SMALL) {
        int* meta  = (int*)d_ws;
        int* order = (int*)((char*)d_ws + 128);
        bucket_count1<<<1, 1024, 0, stream>>>(bidx, meta);
        k_scatter<<<BATCH / 1024, 1024, 0, stream>>>(bidx, meta, order);
        fused_mlp_small<<<NB * 256, 256, 0, stream>>>(x, meta, order, W1, b1, W2, b2, W3, b3, out);
    } else {
        naive_mlp<<<BATCH, 256, 0, stream>>>(x, bidx, W1, b1, W2, b2, W3, b3, out);
    }
}